// Round 10
// baseline (1985.960 us; speedup 1.0000x reference)
//
#include <hip/hip_runtime.h>
#include <math.h>

// Problem constants (B,T,N,D) = (2,64,512,256)
#define B_ 2
#define T_ 64
#define N_ 512
#define D_ 256
#define M_ (B_*T_*N_)            // 65536 rows for the GEMMs
#define PLANE ((size_t)M_*D_)    // 16777216 elements per output plane

typedef unsigned short u16;
typedef __attribute__((ext_vector_type(8))) short bf16x8;
typedef __attribute__((ext_vector_type(4))) float f32x4;

__device__ __forceinline__ u16 f2bf(float f) {
  union { float f; unsigned u; } cv; cv.f = f;
  unsigned u = cv.u;
  return (u16)((u + 0x7FFFu + ((u >> 16) & 1u)) >> 16);   // RNE
}
__device__ __forceinline__ float bf2f(u16 h) {
  union { unsigned u; float f; } cv; cv.u = ((unsigned)h) << 16;
  return cv.f;
}

// 64-lane sum via DPP (VALU-only). Result wave-uniform via readlane 63.
__device__ __forceinline__ float wredsum(float x) {
  x += __uint_as_float(__builtin_amdgcn_update_dpp(0u, __float_as_uint(x), 0x111, 0xf, 0xf, true));
  x += __uint_as_float(__builtin_amdgcn_update_dpp(0u, __float_as_uint(x), 0x112, 0xf, 0xf, true));
  x += __uint_as_float(__builtin_amdgcn_update_dpp(0u, __float_as_uint(x), 0x114, 0xf, 0xf, true));
  x += __uint_as_float(__builtin_amdgcn_update_dpp(0u, __float_as_uint(x), 0x118, 0xf, 0xf, true));
  x += __uint_as_float(__builtin_amdgcn_update_dpp(0u, __float_as_uint(x), 0x142, 0xa, 0xf, true));
  x += __uint_as_float(__builtin_amdgcn_update_dpp(0u, __float_as_uint(x), 0x143, 0xc, 0xf, true));
  return __uint_as_float(__builtin_amdgcn_readlane(__float_as_uint(x), 63));
}
__device__ __forceinline__ float lanebcast(float x, int l) {
  return __uint_as_float(__builtin_amdgcn_readlane(__float_as_uint(x), l));
}

// ---------------------------------------------------------------------------
// Megastep p, larfb version. nb = 8-p blocks.
//   all blocks (p>0): larfb-apply (I - V T^H V^H) of panel p-1 to panel p+role
//     via 3 pipelined passes: W = V^H A (independent dots), w2 = T^H w (LDS
//     matvec), A -= V w2 (independent axpys). No dependent reflector chain.
//   block 0: after applying to its own panel, zgeqr2-factorize panel p
//     (LDS pivot pipeline, DPP reduces, finalized cols -> LDS sfin, batch
//     store to A post-loop), then build T_p (zlarft: Gram + recurrence) and
//     store to Tbuf for the next megastep's apply (and future blocked bwd).
//   p==0: role>0 transpose-init panels; role 0 factorizes panel 0 + T_0.
// ---------------------------------------------------------------------------
__global__ __launch_bounds__(256, 1) void qr_megastep(
    const float* __restrict__ ure_raw, const float* __restrict__ uim_raw,
    float2* __restrict__ A, float2* __restrict__ tau,
    float2* __restrict__ Tbuf, int p)
{
  const int tid = threadIdx.x, lane = tid & 63, w = tid >> 6;
  const int role = blockIdx.x;
  __shared__ float2 sv32[32][256];   // V panel (apply) / sfin (factorize out)
  __shared__ float2 sW[32][32];      // w / w2 per block column; sG in T build
  __shared__ float2 sT[32][32];      // T_{p-1} (apply) then T_p (build)
  __shared__ float2 snext[2][256];
  __shared__ float2 stauP[32];       // taus of panel p-1 (unused by math, kept)
  __shared__ float2 stauN[32];       // taus of panel p (for T build)

  if (p == 0 && role > 0) {
    const int c0 = 32*role;
    const int c = tid & 31, r0 = tid >> 5;
    for (int r8 = 0; r8 < 32; ++r8) {
      int r = r0 + r8*8;
      A[(size_t)(c0+c)*D_ + r] = make_float2(ure_raw[(size_t)r*D_ + c0 + c],
                                             uim_raw[(size_t)r*D_ + c0 + c]);
    }
    return;
  }

  const int j0p  = 32*(p - 1);          // prev-panel start (valid p>=1)
  const int Rp   = 256 - j0p;
  const int MCHp = (Rp + 63) >> 6;

  float2 col[8][4];
  int c0;

  if (p > 0) {
    // ---- stage V_{p-1}, T_{p-1}, taus ----
    #pragma unroll 4
    for (int c = 0; c < 32; ++c) {
      float2 val = make_float2(0.f, 0.f);
      if (tid < Rp) val = A[(size_t)(j0p+c)*D_ + j0p + tid];
      sv32[c][tid] = val;
    }
    {
      const float2* Tg = Tbuf + (size_t)(p-1)*1024;
      float2* sTf = (float2*)sT;
      #pragma unroll
      for (int e = 0; e < 4; ++e) sTf[e*256 + tid] = Tg[e*256 + tid];
    }
    if (tid < 32) stauP[tid] = tau[j0p + tid];

    c0 = 32*(p + role);
    #pragma unroll
    for (int lc = 0; lc < 8; ++lc) {
      int cg = c0 + lc*4 + w;
      #pragma unroll
      for (int m = 0; m < 4; ++m) {
        int rr = m*64 + lane;
        col[lc][m] = make_float2(0.f, 0.f);
        if (m < MCHp && rr < Rp) col[lc][m] = A[(size_t)cg*D_ + j0p + rr];
      }
    }
    __syncthreads();

    // ---- larfb apply: W = V^H a (32 independent dots per column) ----
    #pragma unroll 1
    for (int k = 0; k < 32; ++k) {
      float2 v[4];
      { float2 rv = sv32[k][lane];
        v[0] = (lane > k) ? rv : ((lane == k) ? make_float2(1.f, 0.f)
                                              : make_float2(0.f, 0.f)); }
      #pragma unroll
      for (int m = 1; m < 4; ++m) v[m] = sv32[k][m*64 + lane];
      float wrr[8], wii[8];
      #pragma unroll
      for (int lc = 0; lc < 8; ++lc) {
        wrr[lc] = 0.f; wii[lc] = 0.f;
        #pragma unroll
        for (int m = 0; m < 4; ++m) {
          if (m < MCHp) {
            float2 a = col[lc][m];
            wrr[lc] += v[m].x*a.x + v[m].y*a.y;    // conj(v)*a
            wii[lc] += v[m].x*a.y - v[m].y*a.x;
          }
        }
      }
      #pragma unroll
      for (int lc = 0; lc < 8; ++lc) {
        float gr = wredsum(wrr[lc]), gi = wredsum(wii[lc]);
        if (lane == 0) sW[lc*4 + w][k] = make_float2(gr, gi);
      }
    }
    // ---- w2 = T^H w per column (lanes 0..31; per-wave own columns) ----
    #pragma unroll
    for (int lc = 0; lc < 8; ++lc) {
      int cb = lc*4 + w;
      float2 acc = make_float2(0.f, 0.f);
      if (lane < 32) {
        #pragma unroll 1
        for (int k = 0; k < 32; ++k) {
          float2 t = sT[k][lane];               // conj(T[k][j]), j = lane
          float2 wv = sW[cb][k];
          acc.x += t.x*wv.x + t.y*wv.y;
          acc.y += t.x*wv.y - t.y*wv.x;
        }
      }
      if (lane < 32) sW[cb][lane] = acc;        // overwrite w with w2
    }
    // ---- a -= V w2 ----
    #pragma unroll 1
    for (int k = 0; k < 32; ++k) {
      float2 v[4];
      { float2 rv = sv32[k][lane];
        v[0] = (lane > k) ? rv : ((lane == k) ? make_float2(1.f, 0.f)
                                              : make_float2(0.f, 0.f)); }
      #pragma unroll
      for (int m = 1; m < 4; ++m) v[m] = sv32[k][m*64 + lane];
      #pragma unroll
      for (int lc = 0; lc < 8; ++lc) {
        float2 f = sW[lc*4 + w][k];             // broadcast LDS read
        #pragma unroll
        for (int m = 0; m < 4; ++m) {
          if (m < MCHp) {
            col[lc][m].x -= f.x*v[m].x - f.y*v[m].y;
            col[lc][m].y -= f.x*v[m].y + f.y*v[m].x;
          }
        }
      }
    }

    if (role > 0) {
      // write applied columns back and exit
      #pragma unroll
      for (int lc = 0; lc < 8; ++lc) {
        int cg = c0 + lc*4 + w;
        #pragma unroll
        for (int m = 0; m < 4; ++m) {
          int rr = m*64 + lane;
          if (m < MCHp && rr < Rp) A[(size_t)cg*D_ + j0p + rr] = col[lc][m];
        }
      }
      return;
    }
    __syncthreads();   // block 0: sv32/sT reuse below
  } else {
    // p == 0, role 0: init panel 0 into registers (transposed raw read)
    #pragma unroll
    for (int lc = 0; lc < 8; ++lc) {
      int cg = lc*4 + w;
      #pragma unroll
      for (int m = 0; m < 4; ++m) {
        int rr = m*64 + lane;
        col[lc][m] = make_float2(ure_raw[(size_t)rr*D_ + cg],
                                 uim_raw[(size_t)rr*D_ + cg]);
      }
    }
  }

  // ===== block 0: factorize panel p (window rows [j0w,256)) =====
  const int piv  = (p == 0) ? 0 : 32;
  const int j0w  = (p == 0) ? 0 : j0p;
  const int Rw   = 256 - j0w;
  const int MCHw = (Rw + 63) >> 6;
  float2 (*sfin)[256] = sv32;                   // reuse V buffer for output

  if (w == 0) {
    #pragma unroll
    for (int m = 0; m < 4; ++m) snext[0][m*64 + lane] = col[0][m];
  }
  __syncthreads();

  #pragma unroll 1
  for (int jl = 0; jl < 32; ++jl) {
    const int cur = jl & 1, nxt = cur ^ 1;
    float2 pc[4];
    #pragma unroll
    for (int m = 0; m < 4; ++m) pc[m] = snext[cur][m*64 + lane];
    float part = (lane > piv + jl) ? (pc[0].x*pc[0].x + pc[0].y*pc[0].y) : 0.f;
    if (1 < MCHw) part += pc[1].x*pc[1].x + pc[1].y*pc[1].y;
    if (2 < MCHw) part += pc[2].x*pc[2].x + pc[2].y*pc[2].y;
    if (3 < MCHw) part += pc[3].x*pc[3].x + pc[3].y*pc[3].y;
    part = wredsum(part);
    float ar = lanebcast(pc[0].x, piv + jl), ai = lanebcast(pc[0].y, piv + jl);
    float taur, taui, sclr, scli, beta;
    if (part == 0.f && ai == 0.f) {
      taur = taui = sclr = scli = 0.f; beta = ar;      // H = I
    } else {
      float nrm = sqrtf(ar*ar + ai*ai + part);
      beta = (ar >= 0.f) ? -nrm : nrm;                 // -SIGN(nrm, Re(alpha))
      taur = (beta - ar)/beta; taui = -ai/beta;
      float dr = ar - beta, di = ai, dn = dr*dr + di*di;
      sclr = dr/dn; scli = -di/dn;                     // 1/(alpha-beta)
    }
    if (w == 3 && lane == 0) {
      tau[32*p + jl]  = make_float2(taur, taui);
      stauN[jl]       = make_float2(taur, taui);
    }
    float2 v[4];
    {
      float2 t0 = make_float2(pc[0].x*sclr - pc[0].y*scli,
                              pc[0].x*scli + pc[0].y*sclr);
      v[0] = (lane > piv + jl) ? t0 : ((lane == piv + jl)
                 ? make_float2(1.f, 0.f) : make_float2(0.f, 0.f));
    }
    #pragma unroll
    for (int m = 1; m < 4; ++m)
      v[m] = make_float2(pc[m].x*sclr - pc[m].y*scli,
                         pc[m].x*scli + pc[m].y*sclr);
    if (w == 3) {                                      // finalize col -> LDS
      #pragma unroll
      for (int m = 0; m < 4; ++m) {
        int rr = m*64 + lane;
        float2 o = v[m];
        if (m == 0) {
          if (lane < piv + jl)       o = pc[0];
          else if (lane == piv + jl) o = make_float2(beta, 0.f);
        }
        if (m < MCHw && rr < Rw) sfin[jl][rr] = o, (void)0;
      }
    }
    #pragma unroll
    for (int lc = 0; lc < 8; ++lc) {
      int cl = lc*4 + w;
      if (cl > jl) {
        float wr, wi;
        { float2 a = col[lc][0];
          wr = v[0].x*a.x + v[0].y*a.y; wi = v[0].x*a.y - v[0].y*a.x; }
        if (1 < MCHw) { float2 a = col[lc][1];
          wr += v[1].x*a.x + v[1].y*a.y; wi += v[1].x*a.y - v[1].y*a.x; }
        if (2 < MCHw) { float2 a = col[lc][2];
          wr += v[2].x*a.x + v[2].y*a.y; wi += v[2].x*a.y - v[2].y*a.x; }
        if (3 < MCHw) { float2 a = col[lc][3];
          wr += v[3].x*a.x + v[3].y*a.y; wi += v[3].x*a.y - v[3].y*a.x; }
        wr = wredsum(wr); wi = wredsum(wi);
        float fr = taur*wr + taui*wi;                  // f = conj(tau)*w
        float fi = taur*wi - taui*wr;
        { col[lc][0].x -= fr*v[0].x - fi*v[0].y;
          col[lc][0].y -= fr*v[0].y + fi*v[0].x; }
        if (1 < MCHw) { col[lc][1].x -= fr*v[1].x - fi*v[1].y;
                        col[lc][1].y -= fr*v[1].y + fi*v[1].x; }
        if (2 < MCHw) { col[lc][2].x -= fr*v[2].x - fi*v[2].y;
                        col[lc][2].y -= fr*v[2].y + fi*v[2].x; }
        if (3 < MCHw) { col[lc][3].x -= fr*v[3].x - fi*v[3].y;
                        col[lc][3].y -= fr*v[3].y + fi*v[3].x; }
        if (cl == jl + 1) {
          #pragma unroll
          for (int m = 0; m < 4; ++m) snext[nxt][m*64 + lane] = col[lc][m];
        }
      }
    }
    __syncthreads();
  }

  // ---- batch-write panel columns to A ----
  #pragma unroll 4
  for (int c = 0; c < 32; ++c)
    if (tid < Rw) A[(size_t)(32*p + c)*D_ + j0w + tid] = sfin[c][tid];

  // ---- build T_p (zlarft): Gram into sW, recurrence into sT ----
  {
    float2* sTf = (float2*)sT;
    #pragma unroll
    for (int e = 0; e < 4; ++e) sTf[e*256 + tid] = make_float2(0.f, 0.f);
  }
  __syncthreads();
  for (int j = w; j < 32; j += 4) {
    for (int i = 0; i < j; ++i) {
      float gr = 0.f, gi = 0.f;
      #pragma unroll
      for (int m = 0; m < 4; ++m) {
        int rr = m*64 + lane;
        if (m < MCHw) {
          float2 vi = sfin[i][rr], vj = sfin[j][rr];
          if (rr > piv + j && rr < Rw) {
            gr += vi.x*vj.x + vi.y*vj.y;               // conj(v_i)*v_j
            gi += vi.x*vj.y - vi.y*vj.x;
          }
        }
      }
      gr = wredsum(gr); gi = wredsum(gi);
      float2 vip = sfin[i][piv + j];                   // + conj(v_i[piv+j])*1
      gr += vip.x; gi -= vip.y;
      if (lane == 0) sW[i][j] = make_float2(gr, gi);
    }
  }
  __syncthreads();
  if (w == 0) {
    #pragma unroll 1
    for (int j = 0; j < 32; ++j) {
      float2 tj = stauN[j];
      float2 g = make_float2(0.f, 0.f);
      if (lane < j) g = sW[lane][j];
      float2 tmp = make_float2(-(tj.x*g.x - tj.y*g.y),
                               -(tj.x*g.y + tj.y*g.x));
      if (lane < j) sW[lane][j] = tmp;
      float2 acc = make_float2(0.f, 0.f);
      for (int k = 0; k < 32; ++k) {
        if (k < j) {
          float2 t = sT[lane][k];                      // zero for lane>k
          float2 tm = sW[k][j];
          acc.x += t.x*tm.x - t.y*tm.y;
          acc.y += t.x*tm.y + t.y*tm.x;
        }
      }
      if (lane == j)     sT[lane][j] = tj;
      else if (lane < j) sT[lane][j] = acc;
    }
  }
  __syncthreads();
  {
    float2* Tg = Tbuf + (size_t)p*1024;
    float2* sTf = (float2*)sT;
    #pragma unroll
    for (int e = 0; e < 4; ++e) Tg[e*256 + tid] = sTf[e*256 + tid];
  }
}

// ---------------------------------------------------------------------------
// zung2r: column c of Q = H_0(...H_c(e_c)); one wave per column; depth-2
// register prefetch; DPP reduce. Epilogue writes bf16 B^T matrices.
// ---------------------------------------------------------------------------
__global__ __launch_bounds__(256, 1) void qr_bwd_kernel(
    const float2* __restrict__ A, const float2* __restrict__ tau,
    u16* __restrict__ Benc, u16* __restrict__ Bdec)
{
  const int lane = threadIdx.x & 63;
  const int w = threadIdx.x >> 6;
  const int c = blockIdx.x * 4 + w;          // column 0..255
  __shared__ float2 stau[256];
  if (threadIdx.x < 256) stau[threadIdx.x] = tau[threadIdx.x];
  __syncthreads();

  float2 q[4];
  #pragma unroll
  for (int m = 0; m < 4; ++m) {
    q[m] = make_float2(0.f, 0.f);
    if (m*64 + lane == c) q[m].x = 1.f;      // q = e_c
  }
  float2 a0[4], a1[4];
  #pragma unroll
  for (int m = 0; m < 4; ++m) a0[m] = A[(size_t)c*D_ + m*64 + lane];
  {
    int i1 = (c >= 1) ? c - 1 : 0;
    #pragma unroll
    for (int m = 0; m < 4; ++m) a1[m] = A[(size_t)i1*D_ + m*64 + lane];
  }

  #pragma unroll 1
  for (int i = c; i >= 0; --i) {
    int ip = (i >= 2) ? i - 2 : 0;
    float2 a2[4];
    #pragma unroll
    for (int m = 0; m < 4; ++m) a2[m] = A[(size_t)ip*D_ + m*64 + lane];

    float2 tt = stau[i];
    float2 v[4];
    #pragma unroll
    for (int m = 0; m < 4; ++m) {
      int r = m*64 + lane;
      v[m] = (r > i) ? a0[m] : ((r == i) ? make_float2(1.f, 0.f)
                                         : make_float2(0.f, 0.f));
    }
    float wr = 0.f, wi = 0.f;
    #pragma unroll
    for (int m = 0; m < 4; ++m) {
      wr += v[m].x*q[m].x + v[m].y*q[m].y;   // w += conj(v)*q
      wi += v[m].x*q[m].y - v[m].y*q[m].x;
    }
    wr = wredsum(wr); wi = wredsum(wi);
    float fr = tt.x*wr - tt.y*wi;            // f = tau*w (0 when tau==0)
    float fi = tt.x*wi + tt.y*wr;
    #pragma unroll
    for (int m = 0; m < 4; ++m) {
      q[m].x -= fr*v[m].x - fi*v[m].y;
      q[m].y -= fr*v[m].y + fi*v[m].x;
      a0[m] = a1[m]; a1[m] = a2[m];
    }
  }

  #pragma unroll
  for (int m = 0; m < 4; ++m) {
    int r = m*64 + lane;
    u16 qre = f2bf(q[m].x), qim = f2bf(q[m].y), qimn = f2bf(-q[m].y);
    Benc[(size_t)c*D_ + r]              = qre;
    Benc[(size_t)(c+256)*D_ + r]        = qim;
    Bdec[(size_t)c*512 + r]             = qre;
    Bdec[(size_t)c*512 + 256 + r]       = qimn;
    Bdec[(size_t)(c+256)*512 + r]       = qim;
    Bdec[(size_t)(c+256)*512 + 256 + r] = qre;
  }
}

// ---------------------------------------------------------------------------
// bf16 MFMA GEMM, 128x128 tile, 4 waves, BK=64, 16x16x32 MFMA.
// ---------------------------------------------------------------------------
#define LDT 72

__global__ __launch_bounds__(256) void encode_gemm(
    const float* __restrict__ x, const u16* __restrict__ Bt,
    u16* __restrict__ xer16, u16* __restrict__ xei16)
{
  __shared__ u16 sA[128*LDT];
  __shared__ u16 sB[128*LDT];
  const int tid = threadIdx.x;
  const int lane = tid & 63, w = tid >> 6;
  const int wr = w >> 1, wc = w & 1;
  const int l15 = lane & 15, l4 = lane >> 4;
  const int m0 = blockIdx.x * 128;
  const int n0 = blockIdx.y * 128;
  f32x4 acc[4][4] = {};
  for (int kb = 0; kb < 4; ++kb) {
    #pragma unroll
    for (int i = 0; i < 4; ++i) {
      int chunk = i*256 + tid;
      int row = chunk >> 3, k0 = (chunk & 7) * 8;
      const float* xs = x + (size_t)(m0+row)*D_ + kb*64 + k0;
      float4 f0 = *(const float4*)xs;
      float4 f1 = *(const float4*)(xs + 4);
      int4 va;
      va.x = (int)((unsigned)f2bf(f0.x) | ((unsigned)f2bf(f0.y) << 16));
      va.y = (int)((unsigned)f2bf(f0.z) | ((unsigned)f2bf(f0.w) << 16));
      va.z = (int)((unsigned)f2bf(f1.x) | ((unsigned)f2bf(f1.y) << 16));
      va.w = (int)((unsigned)f2bf(f1.z) | ((unsigned)f2bf(f1.w) << 16));
      int4 vb = *(const int4*)(Bt + (size_t)(n0+row)*D_ + kb*64 + k0);
      *(int4*)&sA[row*LDT + k0] = va;
      *(int4*)&sB[row*LDT + k0] = vb;
    }
    __syncthreads();
    #pragma unroll
    for (int ks = 0; ks < 2; ++ks) {
      bf16x8 af[4], bb[4];
      #pragma unroll
      for (int mf = 0; mf < 4; ++mf)
        af[mf] = *(const bf16x8*)&sA[(wr*64 + mf*16 + l15)*LDT + ks*32 + l4*8];
      #pragma unroll
      for (int nf = 0; nf < 4; ++nf)
        bb[nf] = *(const bf16x8*)&sB[(wc*64 + nf*16 + l15)*LDT + ks*32 + l4*8];
      #pragma unroll
      for (int mf = 0; mf < 4; ++mf)
        #pragma unroll
        for (int nf = 0; nf < 4; ++nf)
          acc[mf][nf] = __builtin_amdgcn_mfma_f32_16x16x32_bf16(
              af[mf], bb[nf], acc[mf][nf], 0, 0, 0);
    }
    __syncthreads();
  }
  #pragma unroll
  for (int mf = 0; mf < 4; ++mf)
    #pragma unroll
    for (int nf = 0; nf < 4; ++nf)
      #pragma unroll
      for (int r = 0; r < 4; ++r) {
        int row = m0 + wr*64 + mf*16 + l4*4 + r;
        int col = n0 + wc*64 + nf*16 + l15;
        float v = acc[mf][nf][r];
        if (col < 256) xer16[(size_t)row*D_ + col] = f2bf(v);
        else           xei16[(size_t)row*D_ + col - 256] = f2bf(-v);
      }
}

__global__ __launch_bounds__(256) void decode_gemm(
    const u16* __restrict__ hre16, const u16* __restrict__ him16,
    const u16* __restrict__ Bt, float* __restrict__ out)
{
  __shared__ u16 sA[128*LDT];
  __shared__ u16 sB[128*LDT];
  const int tid = threadIdx.x;
  const int lane = tid & 63, w = tid >> 6;
  const int wr = w >> 1, wc = w & 1;
  const int l15 = lane & 15, l4 = lane >> 4;
  const int m0 = blockIdx.x * 128;
  const int n0 = blockIdx.y * 128;
  f32x4 acc[4][4] = {};
  for (int kb = 0; kb < 8; ++kb) {
    const u16* aplane = (kb < 4) ? hre16 : him16;
    const int kk = (kb & 3) * 64;
    #pragma unroll
    for (int i = 0; i < 4; ++i) {
      int chunk = i*256 + tid;
      int row = chunk >> 3, k0 = (chunk & 7) * 8;
      int4 va = *(const int4*)(aplane + (size_t)(m0+row)*D_ + kk + k0);
      int4 vb = *(const int4*)(Bt + (size_t)(n0+row)*512 + kb*64 + k0);
      *(int4*)&sA[row*LDT + k0] = va;
      *(int4*)&sB[row*LDT + k0] = vb;
    }
    __syncthreads();
    #pragma unroll
    for (int ks = 0; ks < 2; ++ks) {
      bf16x8 af[4], bb[4];
      #pragma unroll
      for (int mf = 0; mf < 4; ++mf)
        af[mf] = *(const bf16x8*)&sA[(wr*64 + mf*16 + l15)*LDT + ks*32 + l4*8];
      #pragma unroll
      for (int nf = 0; nf < 4; ++nf)
        bb[nf] = *(const bf16x8*)&sB[(wc*64 + nf*16 + l15)*LDT + ks*32 + l4*8];
      #pragma unroll
      for (int mf = 0; mf < 4; ++mf)
        #pragma unroll
        for (int nf = 0; nf < 4; ++nf)
          acc[mf][nf] = __builtin_amdgcn_mfma_f32_16x16x32_bf16(
              af[mf], bb[nf], acc[mf][nf], 0, 0, 0);
    }
    __syncthreads();
  }
  #pragma unroll
  for (int mf = 0; mf < 4; ++mf)
    #pragma unroll
    for (int nf = 0; nf < 4; ++nf)
      #pragma unroll
      for (int r = 0; r < 4; ++r) {
        int row = m0 + wr*64 + mf*16 + l4*4 + r;
        int col = n0 + wc*64 + nf*16 + l15;
        float v = acc[mf][nf][r];
        if (col < 256) out[(size_t)row*D_ + col] = v;
        else           out[PLANE + (size_t)row*D_ + col - 256] = v;
      }
}

// ---------------------------------------------------------------------------
// Scan with fused coefficient computation. One block per (b,n); thread = d.
// ---------------------------------------------------------------------------
__global__ __launch_bounds__(256) void scan_kernel(
  const float* __restrict__ eps, const float* __restrict__ dt,
  const float* __restrict__ lam_re, const float* __restrict__ lam_im,
  const float* __restrict__ noise_raw,
  const u16* __restrict__ xer16, const u16* __restrict__ xei16,
  u16* __restrict__ hre16, u16* __restrict__ him16)
{
  int bx = blockIdx.x;
  int b = bx >> 9, n = bx & 511;
  int d = threadIdx.x;
  __shared__ float sdt[T_];
  if (d < T_) sdt[d] = dt[b*T_ + d];
  __syncthreads();

  float lr = lam_re[d], li = lam_im[d];
  float lam_r = fmaxf(-log1pf(expf(-lr)), -0.3f);     // -softplus(-x), clamp
  float t0 = lam_r + 1e-12f;
  float sgn = (t0 > 0.f) ? 1.f : ((t0 < 0.f) ? -1.f : 0.f);
  float den_re = lam_r + 1e-8f*sgn, den_im = li;      // lam_safe
  float d2 = den_re*den_re + den_im*den_im;
  float nsc = log1pf(expf(noise_raw[d])) * 0.01f;

  float hr = 0.f, hi = 0.f;
  for (int t = 0; t < T_; ++t) {
    float dtv = sdt[t];
    float er = expf(dtv*lam_r);
    float ai = dtv*li;
    float dre = er*cosf(ai), dim_ = er*sinf(ai);
    float nr = dre - 1.f, ni = dim_;
    float fre = (nr*den_re + ni*den_im)/d2;
    float fim = (ni*den_re - nr*den_im)/d2;
    float ns = sqrtf(fmaxf(dtv, 0.f)) * nsc;
    size_t idx = ((size_t)(b*T_ + t)*N_ + n)*D_ + d;
    float xr = bf2f(xer16[idx]), xi = bf2f(xei16[idx]), ep = eps[idx];
    float br = fre*xr - fim*xi + ep*ns;
    float bi = fre*xi + fim*xr;
    float nr2 = dre*hr - dim_*hi + br;
    float ni2 = dre*hi + dim_*hr + bi;
    hr = nr2; hi = ni2;
    hre16[idx] = f2bf(hr); him16[idx] = f2bf(hi);
  }
}

// ---------------------------------------------------------------------------
extern "C" void kernel_launch(void* const* d_in, const int* in_sizes, int n_in,
                              void* d_out, int out_size, void* d_ws, size_t ws_size,
                              hipStream_t stream)
{
  const float* x         = (const float*)d_in[0];
  const float* dt        = (const float*)d_in[1];
  const float* eps       = (const float*)d_in[2];
  const float* ure_raw   = (const float*)d_in[3];
  const float* uim_raw   = (const float*)d_in[4];
  const float* lam_re    = (const float*)d_in[5];
  const float* lam_im    = (const float*)d_in[6];
  const float* noise_raw = (const float*)d_in[7];
  float* out = (float*)d_out;

  // ws layout (132 MB total):
  //   0       A float2[65536]            512 KB
  //   512K    tau float2[256]            2 KB
  //   640K    Tbuf float2[8*1024]        64 KB
  //   1M      Benc bf16 [512][256]       256 KB
  //   1.5M    Bdec bf16 [512][512]       512 KB
  //   4M      hre16 bf16 [M][256] 32 MB
  //   36M     xer16 32 MB
  //   68M     xei16 32 MB
  //   100M    him16 32 MB
  char* ws = (char*)d_ws;
  float2* A    = (float2*)(ws);
  float2* tau  = (float2*)(ws + 524288);
  float2* Tbuf = (float2*)(ws + 655360);
  u16* Benc    = (u16*)(ws + (1<<20));
  u16* Bdec    = (u16*)(ws + 1572864);
  u16* hre16   = (u16*)(ws + ((size_t)4<<20));
  u16* xer16   = (u16*)(ws + ((size_t)36<<20));
  u16* xei16   = (u16*)(ws + ((size_t)68<<20));
  u16* him16   = (u16*)(ws + ((size_t)100<<20));

  for (int p = 0; p < 8; ++p) {
    int nb = (p == 0) ? 8 : (8 - p);
    qr_megastep<<<nb, 256, 0, stream>>>(ure_raw, uim_raw, A, tau, Tbuf, p);
  }
  qr_bwd_kernel<<<64, 256, 0, stream>>>(A, tau, Benc, Bdec);
  encode_gemm<<<dim3(M_/128, 4), 256, 0, stream>>>(x, Benc, xer16, xei16);
  scan_kernel<<<B_*N_, 256, 0, stream>>>(eps, dt, lam_re, lam_im, noise_raw,
                                         xer16, xei16, hre16, him16);
  decode_gemm<<<dim3(M_/128, 4), 256, 0, stream>>>(hre16, him16, Bdec, out);
}

// Round 11
// 1091.865 us; speedup vs baseline: 1.8189x; 1.8189x over previous
//
#include <hip/hip_runtime.h>
#include <math.h>

// Problem constants (B,T,N,D) = (2,64,512,256)
#define B_ 2
#define T_ 64
#define N_ 512
#define D_ 256
#define M_ (B_*T_*N_)            // 65536 rows for the GEMMs
#define PLANE ((size_t)M_*D_)    // 16777216 elements per output plane

typedef unsigned short u16;
typedef __attribute__((ext_vector_type(8))) short bf16x8;
typedef __attribute__((ext_vector_type(4))) float f32x4;

__device__ __forceinline__ u16 f2bf(float f) {
  union { float f; unsigned u; } cv; cv.f = f;
  unsigned u = cv.u;
  return (u16)((u + 0x7FFFu + ((u >> 16) & 1u)) >> 16);   // RNE
}
__device__ __forceinline__ float bf2f(u16 h) {
  union { unsigned u; float f; } cv; cv.u = ((unsigned)h) << 16;
  return cv.f;
}

// 64-lane sum via DPP (VALU-only). Result wave-uniform via readlane 63.
__device__ __forceinline__ float wredsum(float x) {
  x += __uint_as_float(__builtin_amdgcn_update_dpp(0u, __float_as_uint(x), 0x111, 0xf, 0xf, true));
  x += __uint_as_float(__builtin_amdgcn_update_dpp(0u, __float_as_uint(x), 0x112, 0xf, 0xf, true));
  x += __uint_as_float(__builtin_amdgcn_update_dpp(0u, __float_as_uint(x), 0x114, 0xf, 0xf, true));
  x += __uint_as_float(__builtin_amdgcn_update_dpp(0u, __float_as_uint(x), 0x118, 0xf, 0xf, true));
  x += __uint_as_float(__builtin_amdgcn_update_dpp(0u, __float_as_uint(x), 0x142, 0xa, 0xf, true));
  x += __uint_as_float(__builtin_amdgcn_update_dpp(0u, __float_as_uint(x), 0x143, 0xc, 0xf, true));
  return __uint_as_float(__builtin_amdgcn_readlane(__float_as_uint(x), 63));
}
__device__ __forceinline__ float lanebcast(float x, int l) {
  return __uint_as_float(__builtin_amdgcn_readlane(__float_as_uint(x), l));
}

// ---------------------------------------------------------------------------
// Megastep p (round-9 fused-reflector math, 1024 threads = 16 waves =
// 4 waves/SIMD so stalls are TLP-covered; round 8-10 ran 1 wave/SIMD and
// paid every LDS/DPP latency exposed). Wave w owns cols {2w, 2w+1}.
//   role 0:   (p>0: apply V_{p-1} to panel p's 32 cols), factorize panel p.
//   role r>0: p==0: transpose-init panel r; p>0: apply V_{p-1} to panel p+r.
// All register indices compile-time (lc in {0,1} unrolled); pivot column
// flows through LDS snext; DPP reduces.
// ---------------------------------------------------------------------------
__global__ __launch_bounds__(1024, 1) void qr_megastep(
    const float* __restrict__ ure_raw, const float* __restrict__ uim_raw,
    float2* __restrict__ A, float2* __restrict__ tau, int p)
{
  const int tid = threadIdx.x, lane = tid & 63, w = tid >> 6;   // w 0..15
  const int role = blockIdx.x;
  __shared__ float2 sv32[32][256];
  __shared__ float2 stau32[32];
  __shared__ float2 snext[2][256];

  if (p == 0 && role > 0) {
    // transpose-init panel `role`: A[c][r] = raw[r][c]
    const int c0 = 32*role;
    const int c = tid & 31, r0 = tid >> 5;       // r0 0..31
    #pragma unroll
    for (int r8 = 0; r8 < 8; ++r8) {
      int r = r0 + r8*32;
      A[(size_t)(c0+c)*D_ + r] = make_float2(ure_raw[(size_t)r*D_ + c0 + c],
                                             uim_raw[(size_t)r*D_ + c0 + c]);
    }
    return;
  }

  const int j0p  = 32*(p - 1);          // prev-panel start (valid p>=1)
  const int Rp   = 256 - j0p;
  const int MCHp = (Rp + 63) >> 6;

  float2 col[2][4];

  if (p > 0) {
    // ---- stage V_{p-1} (32 cols x 256 window rows) and taus ----
    #pragma unroll
    for (int it = 0; it < 8; ++it) {
      int idx = it*1024 + tid;                   // 0..8191
      int c = idx >> 8, rr = idx & 255;
      float2 val = make_float2(0.f, 0.f);
      if (rr < Rp) val = A[(size_t)(j0p+c)*D_ + j0p + rr];
      sv32[c][rr] = val;
    }
    if (tid < 32) stau32[tid] = tau[j0p + tid];
    const int c0 = (role > 0) ? 32*(p + role) : 32*p;
    #pragma unroll
    for (int lc = 0; lc < 2; ++lc) {
      int cg = c0 + 2*w + lc;
      #pragma unroll
      for (int m = 0; m < 4; ++m) {
        int rr = m*64 + lane;
        col[lc][m] = make_float2(0.f, 0.f);
        if (m < MCHp && rr < Rp) col[lc][m] = A[(size_t)cg*D_ + j0p + rr];
      }
    }
    __syncthreads();

    // ---- fused reflector apply: 32 dependent steps, 2 cols/wave ----
    #pragma unroll 1
    for (int jl = 0; jl < 32; ++jl) {
      float2 tt = stau32[jl];
      float2 v[4];
      { float2 rv = sv32[jl][lane];
        v[0] = (lane > jl) ? rv : ((lane == jl) ? make_float2(1.f, 0.f)
                                                : make_float2(0.f, 0.f)); }
      #pragma unroll
      for (int m = 1; m < 4; ++m) v[m] = sv32[jl][m*64 + lane];
      float wr[2], wi[2];
      #pragma unroll
      for (int lc = 0; lc < 2; ++lc) {
        wr[lc] = 0.f; wi[lc] = 0.f;
        #pragma unroll
        for (int m = 0; m < 4; ++m) {
          if (m < MCHp) {
            float2 a = col[lc][m];
            wr[lc] += v[m].x*a.x + v[m].y*a.y;   // conj(v)*a
            wi[lc] += v[m].x*a.y - v[m].y*a.x;
          }
        }
      }
      #pragma unroll
      for (int lc = 0; lc < 2; ++lc) { wr[lc] = wredsum(wr[lc]);
                                       wi[lc] = wredsum(wi[lc]); }
      #pragma unroll
      for (int lc = 0; lc < 2; ++lc) {
        float fr = tt.x*wr[lc] + tt.y*wi[lc];    // f = conj(tau)*w
        float fi = tt.x*wi[lc] - tt.y*wr[lc];
        #pragma unroll
        for (int m = 0; m < 4; ++m) {
          if (m < MCHp) {
            col[lc][m].x -= fr*v[m].x - fi*v[m].y;
            col[lc][m].y -= fr*v[m].y + fi*v[m].x;
          }
        }
      }
    }

    if (role > 0) {
      #pragma unroll
      for (int lc = 0; lc < 2; ++lc) {
        int cg = 32*(p + role) + 2*w + lc;
        #pragma unroll
        for (int m = 0; m < 4; ++m) {
          int rr = m*64 + lane;
          if (m < MCHp && rr < Rp) A[(size_t)cg*D_ + j0p + rr] = col[lc][m];
        }
      }
      return;
    }
    __syncthreads();
  } else {
    // p == 0, role 0: init panel 0 into registers (transposed raw read)
    #pragma unroll
    for (int lc = 0; lc < 2; ++lc) {
      int cg = 2*w + lc;
      #pragma unroll
      for (int m = 0; m < 4; ++m) {
        int rr = m*64 + lane;
        col[lc][m] = make_float2(ure_raw[(size_t)rr*D_ + cg],
                                 uim_raw[(size_t)rr*D_ + cg]);
      }
    }
  }

  // ===== role 0: factorize panel p (window rows [j0w,256)) =====
  const int piv  = (p == 0) ? 0 : 32;      // pivot row offset (<64: chunk 0)
  const int j0w  = (p == 0) ? 0 : j0p;
  const int Rw   = 256 - j0w;
  const int MCHw = (Rw + 63) >> 6;

  if (w == 0) {
    #pragma unroll
    for (int m = 0; m < 4; ++m) snext[0][m*64 + lane] = col[0][m];
  }
  __syncthreads();

  #pragma unroll 1
  for (int jl = 0; jl < 32; ++jl) {
    const int cur = jl & 1, nxt = cur ^ 1;
    float2 pc[4];
    #pragma unroll
    for (int m = 0; m < 4; ++m) pc[m] = snext[cur][m*64 + lane];
    float part = (lane > piv + jl) ? (pc[0].x*pc[0].x + pc[0].y*pc[0].y) : 0.f;
    if (1 < MCHw) part += pc[1].x*pc[1].x + pc[1].y*pc[1].y;
    if (2 < MCHw) part += pc[2].x*pc[2].x + pc[2].y*pc[2].y;
    if (3 < MCHw) part += pc[3].x*pc[3].x + pc[3].y*pc[3].y;
    part = wredsum(part);
    float ar = lanebcast(pc[0].x, piv + jl), ai = lanebcast(pc[0].y, piv + jl);
    float taur, taui, sclr, scli, beta;
    if (part == 0.f && ai == 0.f) {
      taur = taui = sclr = scli = 0.f; beta = ar;      // H = I
    } else {
      float nrm = sqrtf(ar*ar + ai*ai + part);
      beta = (ar >= 0.f) ? -nrm : nrm;                 // -SIGN(nrm, Re(alpha))
      taur = (beta - ar)/beta; taui = -ai/beta;
      float dr = ar - beta, di = ai, dn = dr*dr + di*di;
      sclr = dr/dn; scli = -di/dn;                     // 1/(alpha-beta)
    }
    if (w == 0 && lane == 0) tau[32*p + jl] = make_float2(taur, taui);
    float2 v[4];
    {
      float2 t0 = make_float2(pc[0].x*sclr - pc[0].y*scli,
                              pc[0].x*scli + pc[0].y*sclr);
      v[0] = (lane > piv + jl) ? t0 : ((lane == piv + jl)
                 ? make_float2(1.f, 0.f) : make_float2(0.f, 0.f));
    }
    #pragma unroll
    for (int m = 1; m < 4; ++m)
      v[m] = make_float2(pc[m].x*sclr - pc[m].y*scli,
                         pc[m].x*scli + pc[m].y*sclr);
    if (w == 0) {                          // pivot column -> A (idle wave)
      #pragma unroll
      for (int m = 0; m < 4; ++m) {
        int rr = m*64 + lane;
        float2 o = v[m];
        if (m == 0) {
          if (lane < piv + jl)       o = pc[0];
          else if (lane == piv + jl) o = make_float2(beta, 0.f);
        }
        if (m < MCHw && rr < Rw) A[(size_t)(32*p + jl)*D_ + j0w + rr] = o;
      }
    }
    #pragma unroll
    for (int lc = 0; lc < 2; ++lc) {
      int cl = 2*w + lc;
      if (cl > jl) {
        float wr, wi;
        { float2 a = col[lc][0];
          wr = v[0].x*a.x + v[0].y*a.y; wi = v[0].x*a.y - v[0].y*a.x; }
        if (1 < MCHw) { float2 a = col[lc][1];
          wr += v[1].x*a.x + v[1].y*a.y; wi += v[1].x*a.y - v[1].y*a.x; }
        if (2 < MCHw) { float2 a = col[lc][2];
          wr += v[2].x*a.x + v[2].y*a.y; wi += v[2].x*a.y - v[2].y*a.x; }
        if (3 < MCHw) { float2 a = col[lc][3];
          wr += v[3].x*a.x + v[3].y*a.y; wi += v[3].x*a.y - v[3].y*a.x; }
        wr = wredsum(wr); wi = wredsum(wi);
        float fr = taur*wr + taui*wi;                  // f = conj(tau)*w
        float fi = taur*wi - taui*wr;
        { col[lc][0].x -= fr*v[0].x - fi*v[0].y;
          col[lc][0].y -= fr*v[0].y + fi*v[0].x; }
        if (1 < MCHw) { col[lc][1].x -= fr*v[1].x - fi*v[1].y;
                        col[lc][1].y -= fr*v[1].y + fi*v[1].x; }
        if (2 < MCHw) { col[lc][2].x -= fr*v[2].x - fi*v[2].y;
                        col[lc][2].y -= fr*v[2].y + fi*v[2].x; }
        if (3 < MCHw) { col[lc][3].x -= fr*v[3].x - fi*v[3].y;
                        col[lc][3].y -= fr*v[3].y + fi*v[3].x; }
        if (cl == jl + 1) {
          #pragma unroll
          for (int m = 0; m < 4; ++m) snext[nxt][m*64 + lane] = col[lc][m];
        }
      }
    }
    __syncthreads();
  }
}

// ---------------------------------------------------------------------------
// zung2r: column c of Q = H_0(...H_c(e_c)); one wave per column; depth-2
// register prefetch; DPP reduce. Epilogue writes bf16 B^T matrices.
// ---------------------------------------------------------------------------
__global__ __launch_bounds__(256, 1) void qr_bwd_kernel(
    const float2* __restrict__ A, const float2* __restrict__ tau,
    u16* __restrict__ Benc, u16* __restrict__ Bdec)
{
  const int lane = threadIdx.x & 63;
  const int w = threadIdx.x >> 6;
  const int c = blockIdx.x * 4 + w;          // column 0..255
  __shared__ float2 stau[256];
  if (threadIdx.x < 256) stau[threadIdx.x] = tau[threadIdx.x];
  __syncthreads();

  float2 q[4];
  #pragma unroll
  for (int m = 0; m < 4; ++m) {
    q[m] = make_float2(0.f, 0.f);
    if (m*64 + lane == c) q[m].x = 1.f;      // q = e_c
  }
  float2 a0[4], a1[4];
  #pragma unroll
  for (int m = 0; m < 4; ++m) a0[m] = A[(size_t)c*D_ + m*64 + lane];
  {
    int i1 = (c >= 1) ? c - 1 : 0;
    #pragma unroll
    for (int m = 0; m < 4; ++m) a1[m] = A[(size_t)i1*D_ + m*64 + lane];
  }

  #pragma unroll 1
  for (int i = c; i >= 0; --i) {
    int ip = (i >= 2) ? i - 2 : 0;
    float2 a2[4];
    #pragma unroll
    for (int m = 0; m < 4; ++m) a2[m] = A[(size_t)ip*D_ + m*64 + lane];

    float2 tt = stau[i];
    float2 v[4];
    #pragma unroll
    for (int m = 0; m < 4; ++m) {
      int r = m*64 + lane;
      v[m] = (r > i) ? a0[m] : ((r == i) ? make_float2(1.f, 0.f)
                                         : make_float2(0.f, 0.f));
    }
    float wr = 0.f, wi = 0.f;
    #pragma unroll
    for (int m = 0; m < 4; ++m) {
      wr += v[m].x*q[m].x + v[m].y*q[m].y;   // w += conj(v)*q
      wi += v[m].x*q[m].y - v[m].y*q[m].x;
    }
    wr = wredsum(wr); wi = wredsum(wi);
    float fr = tt.x*wr - tt.y*wi;            // f = tau*w (0 when tau==0)
    float fi = tt.x*wi + tt.y*wr;
    #pragma unroll
    for (int m = 0; m < 4; ++m) {
      q[m].x -= fr*v[m].x - fi*v[m].y;
      q[m].y -= fr*v[m].y + fi*v[m].x;
      a0[m] = a1[m]; a1[m] = a2[m];
    }
  }

  #pragma unroll
  for (int m = 0; m < 4; ++m) {
    int r = m*64 + lane;
    u16 qre = f2bf(q[m].x), qim = f2bf(q[m].y), qimn = f2bf(-q[m].y);
    Benc[(size_t)c*D_ + r]              = qre;
    Benc[(size_t)(c+256)*D_ + r]        = qim;
    Bdec[(size_t)c*512 + r]             = qre;
    Bdec[(size_t)c*512 + 256 + r]       = qimn;
    Bdec[(size_t)(c+256)*512 + r]       = qim;
    Bdec[(size_t)(c+256)*512 + 256 + r] = qre;
  }
}

// ---------------------------------------------------------------------------
// bf16 MFMA GEMM, 128x128 tile, 4 waves, BK=64, 16x16x32 MFMA.
// encode_gemm reads fp32 x directly and converts during staging.
// ---------------------------------------------------------------------------
#define LDT 72

__global__ __launch_bounds__(256) void encode_gemm(
    const float* __restrict__ x, const u16* __restrict__ Bt,
    u16* __restrict__ xer16, u16* __restrict__ xei16)
{
  __shared__ u16 sA[128*LDT];
  __shared__ u16 sB[128*LDT];
  const int tid = threadIdx.x;
  const int lane = tid & 63, w = tid >> 6;
  const int wr = w >> 1, wc = w & 1;
  const int l15 = lane & 15, l4 = lane >> 4;
  const int m0 = blockIdx.x * 128;
  const int n0 = blockIdx.y * 128;
  f32x4 acc[4][4] = {};
  for (int kb = 0; kb < 4; ++kb) {
    #pragma unroll
    for (int i = 0; i < 4; ++i) {
      int chunk = i*256 + tid;
      int row = chunk >> 3, k0 = (chunk & 7) * 8;
      const float* xs = x + (size_t)(m0+row)*D_ + kb*64 + k0;
      float4 f0 = *(const float4*)xs;
      float4 f1 = *(const float4*)(xs + 4);
      int4 va;
      va.x = (int)((unsigned)f2bf(f0.x) | ((unsigned)f2bf(f0.y) << 16));
      va.y = (int)((unsigned)f2bf(f0.z) | ((unsigned)f2bf(f0.w) << 16));
      va.z = (int)((unsigned)f2bf(f1.x) | ((unsigned)f2bf(f1.y) << 16));
      va.w = (int)((unsigned)f2bf(f1.z) | ((unsigned)f2bf(f1.w) << 16));
      int4 vb = *(const int4*)(Bt + (size_t)(n0+row)*D_ + kb*64 + k0);
      *(int4*)&sA[row*LDT + k0] = va;
      *(int4*)&sB[row*LDT + k0] = vb;
    }
    __syncthreads();
    #pragma unroll
    for (int ks = 0; ks < 2; ++ks) {
      bf16x8 af[4], bb[4];
      #pragma unroll
      for (int mf = 0; mf < 4; ++mf)
        af[mf] = *(const bf16x8*)&sA[(wr*64 + mf*16 + l15)*LDT + ks*32 + l4*8];
      #pragma unroll
      for (int nf = 0; nf < 4; ++nf)
        bb[nf] = *(const bf16x8*)&sB[(wc*64 + nf*16 + l15)*LDT + ks*32 + l4*8];
      #pragma unroll
      for (int mf = 0; mf < 4; ++mf)
        #pragma unroll
        for (int nf = 0; nf < 4; ++nf)
          acc[mf][nf] = __builtin_amdgcn_mfma_f32_16x16x32_bf16(
              af[mf], bb[nf], acc[mf][nf], 0, 0, 0);
    }
    __syncthreads();
  }
  #pragma unroll
  for (int mf = 0; mf < 4; ++mf)
    #pragma unroll
    for (int nf = 0; nf < 4; ++nf)
      #pragma unroll
      for (int r = 0; r < 4; ++r) {
        int row = m0 + wr*64 + mf*16 + l4*4 + r;
        int col = n0 + wc*64 + nf*16 + l15;
        float v = acc[mf][nf][r];
        if (col < 256) xer16[(size_t)row*D_ + col] = f2bf(v);
        else           xei16[(size_t)row*D_ + col - 256] = f2bf(-v);
      }
}

__global__ __launch_bounds__(256) void decode_gemm(
    const u16* __restrict__ hre16, const u16* __restrict__ him16,
    const u16* __restrict__ Bt, float* __restrict__ out)
{
  __shared__ u16 sA[128*LDT];
  __shared__ u16 sB[128*LDT];
  const int tid = threadIdx.x;
  const int lane = tid & 63, w = tid >> 6;
  const int wr = w >> 1, wc = w & 1;
  const int l15 = lane & 15, l4 = lane >> 4;
  const int m0 = blockIdx.x * 128;
  const int n0 = blockIdx.y * 128;
  f32x4 acc[4][4] = {};
  for (int kb = 0; kb < 8; ++kb) {
    const u16* aplane = (kb < 4) ? hre16 : him16;
    const int kk = (kb & 3) * 64;
    #pragma unroll
    for (int i = 0; i < 4; ++i) {
      int chunk = i*256 + tid;
      int row = chunk >> 3, k0 = (chunk & 7) * 8;
      int4 va = *(const int4*)(aplane + (size_t)(m0+row)*D_ + kk + k0);
      int4 vb = *(const int4*)(Bt + (size_t)(n0+row)*512 + kb*64 + k0);
      *(int4*)&sA[row*LDT + k0] = va;
      *(int4*)&sB[row*LDT + k0] = vb;
    }
    __syncthreads();
    #pragma unroll
    for (int ks = 0; ks < 2; ++ks) {
      bf16x8 af[4], bb[4];
      #pragma unroll
      for (int mf = 0; mf < 4; ++mf)
        af[mf] = *(const bf16x8*)&sA[(wr*64 + mf*16 + l15)*LDT + ks*32 + l4*8];
      #pragma unroll
      for (int nf = 0; nf < 4; ++nf)
        bb[nf] = *(const bf16x8*)&sB[(wc*64 + nf*16 + l15)*LDT + ks*32 + l4*8];
      #pragma unroll
      for (int mf = 0; mf < 4; ++mf)
        #pragma unroll
        for (int nf = 0; nf < 4; ++nf)
          acc[mf][nf] = __builtin_amdgcn_mfma_f32_16x16x32_bf16(
              af[mf], bb[nf], acc[mf][nf], 0, 0, 0);
    }
    __syncthreads();
  }
  #pragma unroll
  for (int mf = 0; mf < 4; ++mf)
    #pragma unroll
    for (int nf = 0; nf < 4; ++nf)
      #pragma unroll
      for (int r = 0; r < 4; ++r) {
        int row = m0 + wr*64 + mf*16 + l4*4 + r;
        int col = n0 + wc*64 + nf*16 + l15;
        float v = acc[mf][nf][r];
        if (col < 256) out[(size_t)row*D_ + col] = v;
        else           out[PLANE + (size_t)row*D_ + col - 256] = v;
      }
}

// ---------------------------------------------------------------------------
// Scan with fused coefficient computation. One block per (b,n); thread = d.
// ---------------------------------------------------------------------------
__global__ __launch_bounds__(256) void scan_kernel(
  const float* __restrict__ eps, const float* __restrict__ dt,
  const float* __restrict__ lam_re, const float* __restrict__ lam_im,
  const float* __restrict__ noise_raw,
  const u16* __restrict__ xer16, const u16* __restrict__ xei16,
  u16* __restrict__ hre16, u16* __restrict__ him16)
{
  int bx = blockIdx.x;
  int b = bx >> 9, n = bx & 511;
  int d = threadIdx.x;
  __shared__ float sdt[T_];
  if (d < T_) sdt[d] = dt[b*T_ + d];
  __syncthreads();

  float lr = lam_re[d], li = lam_im[d];
  float lam_r = fmaxf(-log1pf(expf(-lr)), -0.3f);     // -softplus(-x), clamp
  float t0 = lam_r + 1e-12f;
  float sgn = (t0 > 0.f) ? 1.f : ((t0 < 0.f) ? -1.f : 0.f);
  float den_re = lam_r + 1e-8f*sgn, den_im = li;      // lam_safe
  float d2 = den_re*den_re + den_im*den_im;
  float nsc = log1pf(expf(noise_raw[d])) * 0.01f;

  float hr = 0.f, hi = 0.f;
  for (int t = 0; t < T_; ++t) {
    float dtv = sdt[t];
    float er = expf(dtv*lam_r);
    float ai = dtv*li;
    float dre = er*cosf(ai), dim_ = er*sinf(ai);
    float nr = dre - 1.f, ni = dim_;
    float fre = (nr*den_re + ni*den_im)/d2;
    float fim = (ni*den_re - nr*den_im)/d2;
    float ns = sqrtf(fmaxf(dtv, 0.f)) * nsc;
    size_t idx = ((size_t)(b*T_ + t)*N_ + n)*D_ + d;
    float xr = bf2f(xer16[idx]), xi = bf2f(xei16[idx]), ep = eps[idx];
    float br = fre*xr - fim*xi + ep*ns;
    float bi = fre*xi + fim*xr;
    float nr2 = dre*hr - dim_*hi + br;
    float ni2 = dre*hi + dim_*hr + bi;
    hr = nr2; hi = ni2;
    hre16[idx] = f2bf(hr); him16[idx] = f2bf(hi);
  }
}

// ---------------------------------------------------------------------------
extern "C" void kernel_launch(void* const* d_in, const int* in_sizes, int n_in,
                              void* d_out, int out_size, void* d_ws, size_t ws_size,
                              hipStream_t stream)
{
  const float* x         = (const float*)d_in[0];
  const float* dt        = (const float*)d_in[1];
  const float* eps       = (const float*)d_in[2];
  const float* ure_raw   = (const float*)d_in[3];
  const float* uim_raw   = (const float*)d_in[4];
  const float* lam_re    = (const float*)d_in[5];
  const float* lam_im    = (const float*)d_in[6];
  const float* noise_raw = (const float*)d_in[7];
  float* out = (float*)d_out;

  // ws layout (132 MB total):
  //   0       A float2[65536]            512 KB
  //   512K    tau float2[256]            2 KB
  //   1M      Benc bf16 [512][256]       256 KB
  //   1.5M    Bdec bf16 [512][512]       512 KB
  //   4M      hre16 bf16 [M][256] 32 MB
  //   36M     xer16 32 MB
  //   68M     xei16 32 MB
  //   100M    him16 32 MB
  char* ws = (char*)d_ws;
  float2* A    = (float2*)(ws);
  float2* tau  = (float2*)(ws + 524288);
  u16* Benc    = (u16*)(ws + (1<<20));
  u16* Bdec    = (u16*)(ws + 1572864);
  u16* hre16   = (u16*)(ws + ((size_t)4<<20));
  u16* xer16   = (u16*)(ws + ((size_t)36<<20));
  u16* xei16   = (u16*)(ws + ((size_t)68<<20));
  u16* him16   = (u16*)(ws + ((size_t)100<<20));

  for (int p = 0; p < 8; ++p) {
    int nb = (p == 0) ? 8 : (8 - p);
    qr_megastep<<<nb, 1024, 0, stream>>>(ure_raw, uim_raw, A, tau, p);
  }
  qr_bwd_kernel<<<64, 256, 0, stream>>>(A, tau, Benc, Bdec);
  encode_gemm<<<dim3(M_/128, 4), 256, 0, stream>>>(x, Benc, xer16, xei16);
  scan_kernel<<<B_*N_, 256, 0, stream>>>(eps, dt, lam_re, lam_im, noise_raw,
                                         xer16, xei16, hre16, him16);
  decode_gemm<<<dim3(M_/128, 4), 256, 0, stream>>>(hre16, him16, Bdec, out);
}

// Round 12
// 901.234 us; speedup vs baseline: 2.2036x; 1.2115x over previous
//
#include <hip/hip_runtime.h>
#include <math.h>

// Problem constants (B,T,N,D) = (2,64,512,256)
#define B_ 2
#define T_ 64
#define N_ 512
#define D_ 256
#define M_ (B_*T_*N_)            // 65536 rows for the GEMMs
#define PLANE ((size_t)M_*D_)    // 16777216 elements per output plane

typedef unsigned short u16;
typedef __attribute__((ext_vector_type(8))) short bf16x8;
typedef __attribute__((ext_vector_type(4))) float f32x4;

__device__ __forceinline__ u16 f2bf(float f) {
  union { float f; unsigned u; } cv; cv.f = f;
  unsigned u = cv.u;
  return (u16)((u + 0x7FFFu + ((u >> 16) & 1u)) >> 16);   // RNE
}
__device__ __forceinline__ float bf2f(u16 h) {
  union { unsigned u; float f; } cv; cv.u = ((unsigned)h) << 16;
  return cv.f;
}

// 64-lane sum via DPP (VALU-only). Result wave-uniform via readlane 63.
__device__ __forceinline__ float wredsum(float x) {
  x += __uint_as_float(__builtin_amdgcn_update_dpp(0u, __float_as_uint(x), 0x111, 0xf, 0xf, true));
  x += __uint_as_float(__builtin_amdgcn_update_dpp(0u, __float_as_uint(x), 0x112, 0xf, 0xf, true));
  x += __uint_as_float(__builtin_amdgcn_update_dpp(0u, __float_as_uint(x), 0x114, 0xf, 0xf, true));
  x += __uint_as_float(__builtin_amdgcn_update_dpp(0u, __float_as_uint(x), 0x118, 0xf, 0xf, true));
  x += __uint_as_float(__builtin_amdgcn_update_dpp(0u, __float_as_uint(x), 0x142, 0xa, 0xf, true));
  x += __uint_as_float(__builtin_amdgcn_update_dpp(0u, __float_as_uint(x), 0x143, 0xc, 0xf, true));
  return __uint_as_float(__builtin_amdgcn_readlane(__float_as_uint(x), 63));
}
__device__ __forceinline__ float lanebcast(float x, int l) {
  return __uint_as_float(__builtin_amdgcn_readlane(__float_as_uint(x), l));
}

// ---------------------------------------------------------------------------
// Megastep P (TEMPLATED: all window bounds / guards compile-time; round-11
// post-mortem measured ~800 VALU instr/step vs ~200 needed — runtime guards
// and addressing were the bloat). 1024 threads = 16 waves = 4 waves/SIMD.
// Wave w owns cols {2w, 2w+1}.
//   role 0:   (P>0: apply V_{P-1} to panel P's 32 cols), factorize panel P.
//   role r>0: P==0: transpose-init panel r; P>0: apply V_{P-1} to panel P+r.
// No global stores inside the factorize loop (pivot cols -> LDS sfin, taus
// -> LDS stauOut; batch-write after) so no vmcnt(0) drain per s_barrier.
// Apply loop unrolled x4 (barrier-free) to pipeline LDS v-loads.
// ---------------------------------------------------------------------------
template<int P>
__global__ __launch_bounds__(1024, 1) void qr_megastep(
    const float* __restrict__ ure_raw, const float* __restrict__ uim_raw,
    float2* __restrict__ A, float2* __restrict__ tau)
{
  const int tid = threadIdx.x, lane = tid & 63, w = tid >> 6;   // w 0..15
  const int role = blockIdx.x;
  __shared__ float2 sv32[32][256];
  __shared__ float2 sfin[32][256];
  __shared__ float2 stau32[32];
  __shared__ float2 stauOut[32];
  __shared__ float2 snext[2][256];

  constexpr int J0P  = (P > 0) ? 32*(P-1) : 0;   // prev-panel start
  constexpr int RP   = 256 - J0P;
  constexpr int MCHP = (RP + 63) >> 6;
  constexpr int PIV  = (P == 0) ? 0 : 32;        // pivot row offset in window
  constexpr int J0W  = (P == 0) ? 0 : J0P;       // factorize window start
  constexpr int RW   = 256 - J0W;
  constexpr int MCHW = (RW + 63) >> 6;

  if constexpr (P == 0) {
    if (role > 0) {
      // transpose-init panel `role`: A[c][r] = raw[r][c]
      const int c0 = 32*role;
      const int c = tid & 31, r0 = tid >> 5;     // r0 0..31
      #pragma unroll
      for (int r8 = 0; r8 < 8; ++r8) {
        int r = r0 + r8*32;
        A[(size_t)(c0+c)*D_ + r] = make_float2(ure_raw[(size_t)r*D_ + c0 + c],
                                               uim_raw[(size_t)r*D_ + c0 + c]);
      }
      return;
    }
  }

  float2 col[2][4];

  if constexpr (P > 0) {
    // ---- stage V_{P-1} (32 cols x window rows) and taus ----
    #pragma unroll
    for (int it = 0; it < 8; ++it) {
      int idx = it*1024 + tid;                   // 0..8191
      int c = idx >> 8, rr = idx & 255;
      float2 val = make_float2(0.f, 0.f);
      if (rr < RP) val = A[(size_t)(J0P+c)*D_ + J0P + rr];
      sv32[c][rr] = val;
    }
    if (tid < 32) stau32[tid] = tau[J0P + tid];
    const int c0 = (role > 0) ? 32*(P + role) : 32*P;
    #pragma unroll
    for (int lc = 0; lc < 2; ++lc) {
      int cg = c0 + 2*w + lc;
      #pragma unroll
      for (int m = 0; m < 4; ++m) {
        int rr = m*64 + lane;
        col[lc][m] = make_float2(0.f, 0.f);
        if (m < MCHP && rr < RP) col[lc][m] = A[(size_t)cg*D_ + J0P + rr];
      }
    }
    __syncthreads();

    // ---- fused reflector apply: 32 dependent steps, 2 cols/wave ----
    #pragma unroll 4
    for (int jl = 0; jl < 32; ++jl) {
      float2 tt = stau32[jl];
      float2 v[4];
      { float2 rv = sv32[jl][lane];
        v[0] = (lane > jl) ? rv : ((lane == jl) ? make_float2(1.f, 0.f)
                                                : make_float2(0.f, 0.f)); }
      #pragma unroll
      for (int m = 1; m < 4; ++m) v[m] = sv32[jl][m*64 + lane];
      float wr[2], wi[2];
      #pragma unroll
      for (int lc = 0; lc < 2; ++lc) {
        wr[lc] = 0.f; wi[lc] = 0.f;
        #pragma unroll
        for (int m = 0; m < 4; ++m) {
          if (m < MCHP) {
            float2 a = col[lc][m];
            wr[lc] += v[m].x*a.x + v[m].y*a.y;   // conj(v)*a
            wi[lc] += v[m].x*a.y - v[m].y*a.x;
          }
        }
      }
      #pragma unroll
      for (int lc = 0; lc < 2; ++lc) { wr[lc] = wredsum(wr[lc]);
                                       wi[lc] = wredsum(wi[lc]); }
      #pragma unroll
      for (int lc = 0; lc < 2; ++lc) {
        float fr = tt.x*wr[lc] + tt.y*wi[lc];    // f = conj(tau)*w
        float fi = tt.x*wi[lc] - tt.y*wr[lc];
        #pragma unroll
        for (int m = 0; m < 4; ++m) {
          if (m < MCHP) {
            col[lc][m].x -= fr*v[m].x - fi*v[m].y;
            col[lc][m].y -= fr*v[m].y + fi*v[m].x;
          }
        }
      }
    }

    if (role > 0) {
      #pragma unroll
      for (int lc = 0; lc < 2; ++lc) {
        int cg = 32*(P + role) + 2*w + lc;
        #pragma unroll
        for (int m = 0; m < 4; ++m) {
          int rr = m*64 + lane;
          if (m < MCHP && rr < RP) A[(size_t)cg*D_ + J0P + rr] = col[lc][m];
        }
      }
      return;
    }
    __syncthreads();
  } else {
    // P == 0, role 0: init panel 0 into registers (transposed raw read)
    #pragma unroll
    for (int lc = 0; lc < 2; ++lc) {
      int cg = 2*w + lc;
      #pragma unroll
      for (int m = 0; m < 4; ++m) {
        int rr = m*64 + lane;
        col[lc][m] = make_float2(ure_raw[(size_t)rr*D_ + cg],
                                 uim_raw[(size_t)rr*D_ + cg]);
      }
    }
  }

  // ===== role 0: factorize panel P (window rows [J0W,256)) =====
  if (w == 0) {
    #pragma unroll
    for (int m = 0; m < 4; ++m) snext[0][m*64 + lane] = col[0][m];
  }
  __syncthreads();

  #pragma unroll 1
  for (int jl = 0; jl < 32; ++jl) {
    const int cur = jl & 1, nxt = cur ^ 1;
    float2 pc[4];
    #pragma unroll
    for (int m = 0; m < 4; ++m) pc[m] = snext[cur][m*64 + lane];
    float part = (lane > PIV + jl) ? (pc[0].x*pc[0].x + pc[0].y*pc[0].y) : 0.f;
    if (1 < MCHW) part += pc[1].x*pc[1].x + pc[1].y*pc[1].y;
    if (2 < MCHW) part += pc[2].x*pc[2].x + pc[2].y*pc[2].y;
    if (3 < MCHW) part += pc[3].x*pc[3].x + pc[3].y*pc[3].y;
    part = wredsum(part);
    float ar = lanebcast(pc[0].x, PIV + jl), ai = lanebcast(pc[0].y, PIV + jl);
    float taur, taui, sclr, scli, beta;
    if (part == 0.f && ai == 0.f) {
      taur = taui = sclr = scli = 0.f; beta = ar;      // H = I
    } else {
      float nrm = sqrtf(ar*ar + ai*ai + part);
      beta = (ar >= 0.f) ? -nrm : nrm;                 // -SIGN(nrm, Re(alpha))
      taur = (beta - ar)/beta; taui = -ai/beta;
      float dr = ar - beta, di = ai, dn = dr*dr + di*di;
      sclr = dr/dn; scli = -di/dn;                     // 1/(alpha-beta)
    }
    if (w == 0 && lane == 0) stauOut[jl] = make_float2(taur, taui);
    float2 v[4];
    {
      float2 t0 = make_float2(pc[0].x*sclr - pc[0].y*scli,
                              pc[0].x*scli + pc[0].y*sclr);
      v[0] = (lane > PIV + jl) ? t0 : ((lane == PIV + jl)
                 ? make_float2(1.f, 0.f) : make_float2(0.f, 0.f));
    }
    #pragma unroll
    for (int m = 1; m < 4; ++m)
      v[m] = make_float2(pc[m].x*sclr - pc[m].y*scli,
                         pc[m].x*scli + pc[m].y*sclr);
    if (w == 0) {                          // pivot column -> LDS (no global)
      #pragma unroll
      for (int m = 0; m < 4; ++m) {
        int rr = m*64 + lane;
        float2 o = v[m];
        if (m == 0) {
          if (lane < PIV + jl)       o = pc[0];
          else if (lane == PIV + jl) o = make_float2(beta, 0.f);
        }
        if (m < MCHW && rr < RW) sfin[jl][rr] = o;
      }
    }
    #pragma unroll
    for (int lc = 0; lc < 2; ++lc) {
      int cl = 2*w + lc;
      if (cl > jl) {
        float wr, wi;
        { float2 a = col[lc][0];
          wr = v[0].x*a.x + v[0].y*a.y; wi = v[0].x*a.y - v[0].y*a.x; }
        if (1 < MCHW) { float2 a = col[lc][1];
          wr += v[1].x*a.x + v[1].y*a.y; wi += v[1].x*a.y - v[1].y*a.x; }
        if (2 < MCHW) { float2 a = col[lc][2];
          wr += v[2].x*a.x + v[2].y*a.y; wi += v[2].x*a.y - v[2].y*a.x; }
        if (3 < MCHW) { float2 a = col[lc][3];
          wr += v[3].x*a.x + v[3].y*a.y; wi += v[3].x*a.y - v[3].y*a.x; }
        wr = wredsum(wr); wi = wredsum(wi);
        float fr = taur*wr + taui*wi;                  // f = conj(tau)*w
        float fi = taur*wi - taui*wr;
        { col[lc][0].x -= fr*v[0].x - fi*v[0].y;
          col[lc][0].y -= fr*v[0].y + fi*v[0].x; }
        if (1 < MCHW) { col[lc][1].x -= fr*v[1].x - fi*v[1].y;
                        col[lc][1].y -= fr*v[1].y + fi*v[1].x; }
        if (2 < MCHW) { col[lc][2].x -= fr*v[2].x - fi*v[2].y;
                        col[lc][2].y -= fr*v[2].y + fi*v[2].x; }
        if (3 < MCHW) { col[lc][3].x -= fr*v[3].x - fi*v[3].y;
                        col[lc][3].y -= fr*v[3].y + fi*v[3].x; }
        if (cl == jl + 1) {
          #pragma unroll
          for (int m = 0; m < 4; ++m) snext[nxt][m*64 + lane] = col[lc][m];
        }
      }
    }
    __syncthreads();
  }

  // ---- batch-write panel columns + taus to global ----
  #pragma unroll
  for (int it = 0; it < 8; ++it) {
    int idx = it*1024 + tid;
    int c = idx >> 8, rr = idx & 255;
    if (rr < RW) A[(size_t)(32*P + c)*D_ + J0W + rr] = sfin[c][rr];
  }
  if (tid < 32) tau[32*P + tid] = stauOut[tid];
}

// ---------------------------------------------------------------------------
// zung2r: column c of Q = H_0(...H_c(e_c)); one wave per column; depth-2
// register prefetch; DPP reduce. Epilogue writes bf16 B^T matrices.
// ---------------------------------------------------------------------------
__global__ __launch_bounds__(256, 1) void qr_bwd_kernel(
    const float2* __restrict__ A, const float2* __restrict__ tau,
    u16* __restrict__ Benc, u16* __restrict__ Bdec)
{
  const int lane = threadIdx.x & 63;
  const int w = threadIdx.x >> 6;
  const int c = blockIdx.x * 4 + w;          // column 0..255
  __shared__ float2 stau[256];
  if (threadIdx.x < 256) stau[threadIdx.x] = tau[threadIdx.x];
  __syncthreads();

  float2 q[4];
  #pragma unroll
  for (int m = 0; m < 4; ++m) {
    q[m] = make_float2(0.f, 0.f);
    if (m*64 + lane == c) q[m].x = 1.f;      // q = e_c
  }
  float2 a0[4], a1[4];
  #pragma unroll
  for (int m = 0; m < 4; ++m) a0[m] = A[(size_t)c*D_ + m*64 + lane];
  {
    int i1 = (c >= 1) ? c - 1 : 0;
    #pragma unroll
    for (int m = 0; m < 4; ++m) a1[m] = A[(size_t)i1*D_ + m*64 + lane];
  }

  #pragma unroll 1
  for (int i = c; i >= 0; --i) {
    int ip = (i >= 2) ? i - 2 : 0;
    float2 a2[4];
    #pragma unroll
    for (int m = 0; m < 4; ++m) a2[m] = A[(size_t)ip*D_ + m*64 + lane];

    float2 tt = stau[i];
    float2 v[4];
    #pragma unroll
    for (int m = 0; m < 4; ++m) {
      int r = m*64 + lane;
      v[m] = (r > i) ? a0[m] : ((r == i) ? make_float2(1.f, 0.f)
                                         : make_float2(0.f, 0.f));
    }
    float wr = 0.f, wi = 0.f;
    #pragma unroll
    for (int m = 0; m < 4; ++m) {
      wr += v[m].x*q[m].x + v[m].y*q[m].y;   // w += conj(v)*q
      wi += v[m].x*q[m].y - v[m].y*q[m].x;
    }
    wr = wredsum(wr); wi = wredsum(wi);
    float fr = tt.x*wr - tt.y*wi;            // f = tau*w (0 when tau==0)
    float fi = tt.x*wi + tt.y*wr;
    #pragma unroll
    for (int m = 0; m < 4; ++m) {
      q[m].x -= fr*v[m].x - fi*v[m].y;
      q[m].y -= fr*v[m].y + fi*v[m].x;
      a0[m] = a1[m]; a1[m] = a2[m];
    }
  }

  #pragma unroll
  for (int m = 0; m < 4; ++m) {
    int r = m*64 + lane;
    u16 qre = f2bf(q[m].x), qim = f2bf(q[m].y), qimn = f2bf(-q[m].y);
    Benc[(size_t)c*D_ + r]              = qre;
    Benc[(size_t)(c+256)*D_ + r]        = qim;
    Bdec[(size_t)c*512 + r]             = qre;
    Bdec[(size_t)c*512 + 256 + r]       = qimn;
    Bdec[(size_t)(c+256)*512 + r]       = qim;
    Bdec[(size_t)(c+256)*512 + 256 + r] = qre;
  }
}

// ---------------------------------------------------------------------------
// bf16 MFMA GEMM, 128x128 tile, 4 waves, BK=64, 16x16x32 MFMA.
// encode_gemm reads fp32 x directly and converts during staging.
// ---------------------------------------------------------------------------
#define LDT 72

__global__ __launch_bounds__(256) void encode_gemm(
    const float* __restrict__ x, const u16* __restrict__ Bt,
    u16* __restrict__ xer16, u16* __restrict__ xei16)
{
  __shared__ u16 sA[128*LDT];
  __shared__ u16 sB[128*LDT];
  const int tid = threadIdx.x;
  const int lane = tid & 63, w = tid >> 6;
  const int wr = w >> 1, wc = w & 1;
  const int l15 = lane & 15, l4 = lane >> 4;
  const int m0 = blockIdx.x * 128;
  const int n0 = blockIdx.y * 128;
  f32x4 acc[4][4] = {};
  for (int kb = 0; kb < 4; ++kb) {
    #pragma unroll
    for (int i = 0; i < 4; ++i) {
      int chunk = i*256 + tid;
      int row = chunk >> 3, k0 = (chunk & 7) * 8;
      const float* xs = x + (size_t)(m0+row)*D_ + kb*64 + k0;
      float4 f0 = *(const float4*)xs;
      float4 f1 = *(const float4*)(xs + 4);
      int4 va;
      va.x = (int)((unsigned)f2bf(f0.x) | ((unsigned)f2bf(f0.y) << 16));
      va.y = (int)((unsigned)f2bf(f0.z) | ((unsigned)f2bf(f0.w) << 16));
      va.z = (int)((unsigned)f2bf(f1.x) | ((unsigned)f2bf(f1.y) << 16));
      va.w = (int)((unsigned)f2bf(f1.z) | ((unsigned)f2bf(f1.w) << 16));
      int4 vb = *(const int4*)(Bt + (size_t)(n0+row)*D_ + kb*64 + k0);
      *(int4*)&sA[row*LDT + k0] = va;
      *(int4*)&sB[row*LDT + k0] = vb;
    }
    __syncthreads();
    #pragma unroll
    for (int ks = 0; ks < 2; ++ks) {
      bf16x8 af[4], bb[4];
      #pragma unroll
      for (int mf = 0; mf < 4; ++mf)
        af[mf] = *(const bf16x8*)&sA[(wr*64 + mf*16 + l15)*LDT + ks*32 + l4*8];
      #pragma unroll
      for (int nf = 0; nf < 4; ++nf)
        bb[nf] = *(const bf16x8*)&sB[(wc*64 + nf*16 + l15)*LDT + ks*32 + l4*8];
      #pragma unroll
      for (int mf = 0; mf < 4; ++mf)
        #pragma unroll
        for (int nf = 0; nf < 4; ++nf)
          acc[mf][nf] = __builtin_amdgcn_mfma_f32_16x16x32_bf16(
              af[mf], bb[nf], acc[mf][nf], 0, 0, 0);
    }
    __syncthreads();
  }
  #pragma unroll
  for (int mf = 0; mf < 4; ++mf)
    #pragma unroll
    for (int nf = 0; nf < 4; ++nf)
      #pragma unroll
      for (int r = 0; r < 4; ++r) {
        int row = m0 + wr*64 + mf*16 + l4*4 + r;
        int col = n0 + wc*64 + nf*16 + l15;
        float v = acc[mf][nf][r];
        if (col < 256) xer16[(size_t)row*D_ + col] = f2bf(v);
        else           xei16[(size_t)row*D_ + col - 256] = f2bf(-v);
      }
}

__global__ __launch_bounds__(256) void decode_gemm(
    const u16* __restrict__ hre16, const u16* __restrict__ him16,
    const u16* __restrict__ Bt, float* __restrict__ out)
{
  __shared__ u16 sA[128*LDT];
  __shared__ u16 sB[128*LDT];
  const int tid = threadIdx.x;
  const int lane = tid & 63, w = tid >> 6;
  const int wr = w >> 1, wc = w & 1;
  const int l15 = lane & 15, l4 = lane >> 4;
  const int m0 = blockIdx.x * 128;
  const int n0 = blockIdx.y * 128;
  f32x4 acc[4][4] = {};
  for (int kb = 0; kb < 8; ++kb) {
    const u16* aplane = (kb < 4) ? hre16 : him16;
    const int kk = (kb & 3) * 64;
    #pragma unroll
    for (int i = 0; i < 4; ++i) {
      int chunk = i*256 + tid;
      int row = chunk >> 3, k0 = (chunk & 7) * 8;
      int4 va = *(const int4*)(aplane + (size_t)(m0+row)*D_ + kk + k0);
      int4 vb = *(const int4*)(Bt + (size_t)(n0+row)*512 + kb*64 + k0);
      *(int4*)&sA[row*LDT + k0] = va;
      *(int4*)&sB[row*LDT + k0] = vb;
    }
    __syncthreads();
    #pragma unroll
    for (int ks = 0; ks < 2; ++ks) {
      bf16x8 af[4], bb[4];
      #pragma unroll
      for (int mf = 0; mf < 4; ++mf)
        af[mf] = *(const bf16x8*)&sA[(wr*64 + mf*16 + l15)*LDT + ks*32 + l4*8];
      #pragma unroll
      for (int nf = 0; nf < 4; ++nf)
        bb[nf] = *(const bf16x8*)&sB[(wc*64 + nf*16 + l15)*LDT + ks*32 + l4*8];
      #pragma unroll
      for (int mf = 0; mf < 4; ++mf)
        #pragma unroll
        for (int nf = 0; nf < 4; ++nf)
          acc[mf][nf] = __builtin_amdgcn_mfma_f32_16x16x32_bf16(
              af[mf], bb[nf], acc[mf][nf], 0, 0, 0);
    }
    __syncthreads();
  }
  #pragma unroll
  for (int mf = 0; mf < 4; ++mf)
    #pragma unroll
    for (int nf = 0; nf < 4; ++nf)
      #pragma unroll
      for (int r = 0; r < 4; ++r) {
        int row = m0 + wr*64 + mf*16 + l4*4 + r;
        int col = n0 + wc*64 + nf*16 + l15;
        float v = acc[mf][nf][r];
        if (col < 256) out[(size_t)row*D_ + col] = v;
        else           out[PLANE + (size_t)row*D_ + col - 256] = v;
      }
}

// ---------------------------------------------------------------------------
// Scan with fused coefficient computation. One block per (b,n); thread = d.
// ---------------------------------------------------------------------------
__global__ __launch_bounds__(256) void scan_kernel(
  const float* __restrict__ eps, const float* __restrict__ dt,
  const float* __restrict__ lam_re, const float* __restrict__ lam_im,
  const float* __restrict__ noise_raw,
  const u16* __restrict__ xer16, const u16* __restrict__ xei16,
  u16* __restrict__ hre16, u16* __restrict__ him16)
{
  int bx = blockIdx.x;
  int b = bx >> 9, n = bx & 511;
  int d = threadIdx.x;
  __shared__ float sdt[T_];
  if (d < T_) sdt[d] = dt[b*T_ + d];
  __syncthreads();

  float lr = lam_re[d], li = lam_im[d];
  float lam_r = fmaxf(-log1pf(expf(-lr)), -0.3f);     // -softplus(-x), clamp
  float t0 = lam_r + 1e-12f;
  float sgn = (t0 > 0.f) ? 1.f : ((t0 < 0.f) ? -1.f : 0.f);
  float den_re = lam_r + 1e-8f*sgn, den_im = li;      // lam_safe
  float d2 = den_re*den_re + den_im*den_im;
  float nsc = log1pf(expf(noise_raw[d])) * 0.01f;

  float hr = 0.f, hi = 0.f;
  for (int t = 0; t < T_; ++t) {
    float dtv = sdt[t];
    float er = expf(dtv*lam_r);
    float ai = dtv*li;
    float dre = er*cosf(ai), dim_ = er*sinf(ai);
    float nr = dre - 1.f, ni = dim_;
    float fre = (nr*den_re + ni*den_im)/d2;
    float fim = (ni*den_re - nr*den_im)/d2;
    float ns = sqrtf(fmaxf(dtv, 0.f)) * nsc;
    size_t idx = ((size_t)(b*T_ + t)*N_ + n)*D_ + d;
    float xr = bf2f(xer16[idx]), xi = bf2f(xei16[idx]), ep = eps[idx];
    float br = fre*xr - fim*xi + ep*ns;
    float bi = fre*xi + fim*xr;
    float nr2 = dre*hr - dim_*hi + br;
    float ni2 = dre*hi + dim_*hr + bi;
    hr = nr2; hi = ni2;
    hre16[idx] = f2bf(hr); him16[idx] = f2bf(hi);
  }
}

// ---------------------------------------------------------------------------
extern "C" void kernel_launch(void* const* d_in, const int* in_sizes, int n_in,
                              void* d_out, int out_size, void* d_ws, size_t ws_size,
                              hipStream_t stream)
{
  const float* x         = (const float*)d_in[0];
  const float* dt        = (const float*)d_in[1];
  const float* eps       = (const float*)d_in[2];
  const float* ure_raw   = (const float*)d_in[3];
  const float* uim_raw   = (const float*)d_in[4];
  const float* lam_re    = (const float*)d_in[5];
  const float* lam_im    = (const float*)d_in[6];
  const float* noise_raw = (const float*)d_in[7];
  float* out = (float*)d_out;

  // ws layout (132 MB total):
  //   0       A float2[65536]            512 KB
  //   512K    tau float2[256]            2 KB
  //   1M      Benc bf16 [512][256]       256 KB
  //   1.5M    Bdec bf16 [512][512]       512 KB
  //   4M      hre16 bf16 [M][256] 32 MB
  //   36M     xer16 32 MB
  //   68M     xei16 32 MB
  //   100M    him16 32 MB
  char* ws = (char*)d_ws;
  float2* A    = (float2*)(ws);
  float2* tau  = (float2*)(ws + 524288);
  u16* Benc    = (u16*)(ws + (1<<20));
  u16* Bdec    = (u16*)(ws + 1572864);
  u16* hre16   = (u16*)(ws + ((size_t)4<<20));
  u16* xer16   = (u16*)(ws + ((size_t)36<<20));
  u16* xei16   = (u16*)(ws + ((size_t)68<<20));
  u16* him16   = (u16*)(ws + ((size_t)100<<20));

  qr_megastep<0><<<8, 1024, 0, stream>>>(ure_raw, uim_raw, A, tau);
  qr_megastep<1><<<7, 1024, 0, stream>>>(ure_raw, uim_raw, A, tau);
  qr_megastep<2><<<6, 1024, 0, stream>>>(ure_raw, uim_raw, A, tau);
  qr_megastep<3><<<5, 1024, 0, stream>>>(ure_raw, uim_raw, A, tau);
  qr_megastep<4><<<4, 1024, 0, stream>>>(ure_raw, uim_raw, A, tau);
  qr_megastep<5><<<3, 1024, 0, stream>>>(ure_raw, uim_raw, A, tau);
  qr_megastep<6><<<2, 1024, 0, stream>>>(ure_raw, uim_raw, A, tau);
  qr_megastep<7><<<1, 1024, 0, stream>>>(ure_raw, uim_raw, A, tau);
  qr_bwd_kernel<<<64, 256, 0, stream>>>(A, tau, Benc, Bdec);
  encode_gemm<<<dim3(M_/128, 4), 256, 0, stream>>>(x, Benc, xer16, xei16);
  scan_kernel<<<B_*N_, 256, 0, stream>>>(eps, dt, lam_re, lam_im, noise_raw,
                                         xer16, xei16, hre16, him16);
  decode_gemm<<<dim3(M_/128, 4), 256, 0, stream>>>(hre16, him16, Bdec, out);
}